// Round 12
// baseline (82.974 us; speedup 1.0000x reference)
//
#include <hip/hip_runtime.h>
#include <hip/hip_bf16.h>
#include <stdint.h>

#define BB 8
#define NN 2048
#define MM 2048
#define CC 256

typedef __attribute__((ext_vector_type(8))) short short8;
typedef __attribute__((ext_vector_type(4))) float f32x4;

__device__ __forceinline__ void gl_lds16(const void* g, void* l) {
    __builtin_amdgcn_global_load_lds(
        (const __attribute__((address_space(1))) void*)g,
        (__attribute__((address_space(3))) void*)l, 16, 0, 0);
}

__device__ __forceinline__ unsigned short f2bf(float f) {
    __hip_bfloat16 h = __float2bfloat16(f);
    return *reinterpret_cast<unsigned short*>(&h);
}

// ---------------- streaming pre-pass: zpack (blocks 0..2047) + norm (2048..6143) ----
// zpack: z tile 128x128 staged to LDS coalesced, packed to 2-bit codes in the
//   fused kernel's per-(tile,thread) order: slot s=(m*4+r)*2+n, code 0/1/2.
//   codes[(((b*16+by)*16+bx)*512 + tid)] = uint2 (proven R3/R4).
// norm: one wave per row of C=256 floats; A/B bf16 layouts (proven R5/R11):
//   A: row*512 + c*64 + kbL*16 + (lane&1)*8, kbL = kb ^ ((row>>1)&3)
//   B: batch*1MiB + ((r>>4)*8 + c)*1024 + kbL*256 + (r&15)*16 + ...
__global__ __launch_bounds__(512) void stream_kernel(
    const int* __restrict__ z,
    const float* __restrict__ x1, const float* __restrict__ x2,
    char* __restrict__ outA, char* __restrict__ outB,
    uint2* __restrict__ codes,
    float* __restrict__ lsum, unsigned int* __restrict__ vcnt,
    unsigned int* __restrict__ flags, unsigned int* __restrict__ done) {

    __shared__ int zt[128 * 132];
    const int bid = blockIdx.x;
    const int tid = threadIdx.x;

    if (bid == 0 && tid < 8) {
        lsum[tid] = 0.0f; vcnt[tid] = 0u; flags[tid] = 0u; flags[BB + tid] = 0u;
        if (tid == 0) *done = 0u;
    }

    if (bid < 2048) {
        // ---------------- zpack ----------------
        const int b  = bid & 7;
        const int r2 = bid >> 3;
        const int by = r2 & 15;         // n-panel (128 rows)
        const int bx = r2 >> 4;         // m-tile  (128 cols)
        const int n0 = by * 128, m0 = bx * 128;

#pragma unroll
        for (int i = 0; i < 8; i++) {
            int idx = i * 512 + tid;      // 0..4095 int4-units
            int row = idx >> 5;           // 0..127
            int col = (idx & 31) * 4;     // 0..124
            int4 v = *reinterpret_cast<const int4*>(
                z + ((size_t)b * NN + n0 + row) * MM + m0 + col);
            *reinterpret_cast<int4*>(&zt[row * 132 + col]) = v;
        }
        __syncthreads();

        const int lane = tid & 63, wid = tid >> 6;
        const int wr = wid >> 2, wc = wid & 3;
        const int l15 = lane & 15, q4 = (lane >> 4) << 2;

        uint32_t w0 = 0u, w1 = 0u;
#pragma unroll
        for (int m = 0; m < 4; m++)
#pragma unroll
            for (int r = 0; r < 4; r++)
#pragma unroll
                for (int n = 0; n < 2; n++) {
                    int v = zt[(wr * 64 + m * 16 + q4 + r) * 132 + wc * 32 + l15 + n * 16];
                    uint32_t code = (v == 0) ? 0u : ((v > 0) ? 1u : 2u);
                    int s = (m * 4 + r) * 2 + n;
                    if (s < 16) w0 |= code << (s * 2);
                    else        w1 |= code << ((s - 16) * 2);
                }
        codes[(size_t)((b * 16 + by) * 16 + bx) * 512 + tid] = make_uint2(w0, w1);
    } else {
        // ---------------- norm + cast ----------------
        int gwave = ((bid - 2048) << 3) + (tid >> 6);   // 0..32767
        int lane  = tid & 63;
        bool isA = gwave < BB * NN;
        const float* src = isA ? x1 : x2;
        int row = isA ? gwave : gwave - BB * NN;
        float4 v = reinterpret_cast<const float4*>(src + (size_t)row * CC)[lane];
        float ss = v.x * v.x + v.y * v.y + v.z * v.z + v.w * v.w;
#pragma unroll
        for (int off = 32; off; off >>= 1) ss += __shfl_xor(ss, off);
        float inv = 1.0f / fmaxf(sqrtf(ss), 1e-8f);
        ushort4 h;
        h.x = f2bf(v.x * inv); h.y = f2bf(v.y * inv);
        h.z = f2bf(v.z * inv); h.w = f2bf(v.w * inv);
        int c   = lane >> 3;
        int kb  = (lane >> 1) & 3;
        int kbL = kb ^ ((row >> 1) & 3);
        char* p;
        if (isA) {
            p = outA + (size_t)row * 512 + c * 64 + kbL * 16 + (lane & 1) * 8;
        } else {
            int b = row >> 11, r = row & 2047;
            p = outB + (size_t)b * 1048576 + (size_t)((r >> 4) * 8 + c) * 1024
                     + kbL * 256 + (r & 15) * 16 + (lane & 1) * 8;
        }
        *reinterpret_cast<ushort4*>(p) = h;
    }
}

// ---------------- fused MFMA cos-sim + BCE reduce + finalize ----------------
// R11 structure: 512 blocks (XCD b=blockIdx&7, A/B L2-resident), 128-row
// A-panel full-K in LDS, 4 m-tiles of 128. z replaced by one uint2 code
// load per tile (epilogue never touches HBM-latency data).
__global__ __launch_bounds__(512) void fused_mfma_kernel(
    const uint2* __restrict__ codes,
    const char* __restrict__ nA, const char* __restrict__ nB,
    const float* __restrict__ tptr, const float* __restrict__ bptr,
    float* __restrict__ lsum, unsigned int* __restrict__ vcnt,
    unsigned int* __restrict__ flags, unsigned int* __restrict__ done,
    float* __restrict__ out) {

    __shared__ __align__(16) char ldsA[65536];   // 8 k-chunks x 128 rows x 64 B
    __shared__ float        s_sum[8];
    __shared__ unsigned int s_cnt[8];
    __shared__ unsigned int s_flag[2];

    const int flat = blockIdx.x;
    const int b    = flat & 7;           // XCD id == batch
    const int rest = flat >> 3;          // 0..63
    const int ny   = rest & 15;          // n-panel index
    const int n0   = ny * 128;
    const int mq   = rest >> 4;          // 0..3
    const int tid  = threadIdx.x, lane = tid & 63, wid = tid >> 6;
    const int wr = wid >> 2, wc = wid & 3, l15 = lane & 15;
    const int kbL = (lane >> 4) ^ ((l15 >> 1) & 3);

    // ---- A staging: wave `wid` stages k-chunk c=wid, 128 rows (8 x 1 KiB) ----
    {
        const char* src = nA + ((size_t)b * NN + n0) * 512
                        + (size_t)(lane >> 2) * 512 + wid * 64 + (lane & 3) * 16;
        char* dst = ldsA + wid * 8192;
#pragma unroll
        for (int g = 0; g < 8; g++)
            gl_lds16(src + (size_t)g * 8192, dst + g * 1024);
    }

    const char* gB0 = nB + (size_t)b * 1048576 + (size_t)mq * 262144
                    + kbL * 256 + l15 * 16;

    const float tv = *tptr;
    const float bs = *bptr;
    const float LOG2E = 1.4426950408889634f;
    const float LN2   = 0.6931471805599453f;

    __syncthreads();   // A-slab resident

    float lsu = 0.0f;
    int   lcnt = 0;
    bool  anyp = false, anyn = false;

#pragma unroll
    for (int mt = 0; mt < 4; mt++) {
        const char* gBt = gB0 + mt * 65536;

        // ---- bulk-issue: 1 code uint2 + 16 B fragments, all in flight ----
        uint2 zc = codes[(size_t)((b * 16 + ny) * 16 + (mq * 4 + mt)) * 512 + tid];

        short8 bfr[8][2];
#pragma unroll
        for (int c = 0; c < 8; c++)
#pragma unroll
            for (int n = 0; n < 2; n++)
                bfr[c][n] = *reinterpret_cast<const short8*>(
                    gBt + (wc * 2 + n) * 8192 + c * 1024);

        __builtin_amdgcn_sched_barrier(0);   // loads may not sink into MFMA chain

        // ---- MFMA over full K (wave-tile 64x32) ----
        f32x4 acc[4][2] = {};
#pragma unroll
        for (int c = 0; c < 8; c++) {
            short8 af[4];
#pragma unroll
            for (int m = 0; m < 4; m++)
                af[m] = *reinterpret_cast<const short8*>(
                    ldsA + c * 8192 + (wr * 64 + m * 16 + l15) * 64 + kbL * 16);
#pragma unroll
            for (int m = 0; m < 4; m++) {
                acc[m][0] = __builtin_amdgcn_mfma_f32_16x16x32_bf16(af[m], bfr[c][0], acc[m][0], 0, 0, 0);
                acc[m][1] = __builtin_amdgcn_mfma_f32_16x16x32_bf16(af[m], bfr[c][1], acc[m][1], 0, 0, 0);
            }
        }

        // ---- fused epilogue (codes in registers; exp2-domain log-sigmoid) ----
#pragma unroll
        for (int m = 0; m < 4; m++)
#pragma unroll
            for (int r = 0; r < 4; r++)
#pragma unroll
                for (int n = 0; n < 2; n++) {
                    int s = (m * 4 + r) * 2 + n;
                    uint32_t word = (s < 16) ? zc.x : zc.y;
                    uint32_t code = (word >> ((s & 15) * 2)) & 3u;
                    float cs = acc[m][n][r];
                    float pp = fmaf(tv, cs, -bs);
                    float y  = (code == 2u) ? -pp : pp;
                    float e  = __builtin_amdgcn_exp2f(-fabsf(y) * LOG2E);
                    float lg = __builtin_amdgcn_logf(1.0f + e);
                    float ls = fminf(y, 0.0f) - LN2 * lg;
                    if (code) { lsu += ls; lcnt++; }
                    anyp |= (code == 1u);
                    anyn |= (code == 2u);
                }
    }

    // ---------------- block reduction ----------------
#pragma unroll
    for (int off = 32; off; off >>= 1) {
        lsu  += __shfl_down(lsu, off);
        lcnt += __shfl_down(lcnt, off);
    }
    unsigned long long mp = __ballot(anyp);
    unsigned long long mn = __ballot(anyn);

    __syncthreads();
    if (tid < 2) s_flag[tid] = 0u;
    __syncthreads();
    if (lane == 0) {
        s_sum[wid] = lsu;
        s_cnt[wid] = (unsigned int)lcnt;
        if (mp) atomicOr(&s_flag[0], 1u);
        if (mn) atomicOr(&s_flag[1], 1u);
    }
    __syncthreads();
    if (tid == 0) {
        float ts = 0.f; unsigned int tc = 0u;
#pragma unroll
        for (int w = 0; w < 8; w++) { ts += s_sum[w]; tc += s_cnt[w]; }
        atomicAdd(&lsum[b], ts);
        atomicAdd(&vcnt[b], tc);
        if (s_flag[0]) atomicOr(&flags[b], 1u);
        if (s_flag[1]) atomicOr(&flags[BB + b], 1u);
        __threadfence();
        unsigned int old = atomicAdd(done, 1u);
        if (old == gridDim.x - 1) {
            __threadfence();
            double s = 0.0, c = 0.0;
#pragma unroll
            for (int bb = 0; bb < BB; bb++) {
                unsigned int fp = atomicOr(&flags[bb], 0u);
                unsigned int fn = atomicOr(&flags[BB + bb], 0u);
                float        sv = atomicAdd(&lsum[bb], 0.0f);
                unsigned int cv = atomicAdd(&vcnt[bb], 0u);
                if (fp && fn) { s += (double)sv; c += (double)cv; }
            }
            out[0] = (float)(-s / c);
        }
    }
}

extern "C" void kernel_launch(void* const* d_in, const int* in_sizes, int n_in,
                              void* d_out, int out_size, void* d_ws, size_t ws_size,
                              hipStream_t stream) {
    const int*   z   = (const int*)  d_in[0];
    const float* x1  = (const float*)d_in[1];
    const float* x2  = (const float*)d_in[2];
    const float* tp  = (const float*)d_in[3];
    const float* bp  = (const float*)d_in[4];
    float* out = (float*)d_out;

    char* ws = (char*)d_ws;
    char*  normA = ws;                                           // 8 MiB
    char*  normB = ws + (size_t)BB * NN * 512;                   // 8 MiB
    uint2* codes = (uint2*)(ws + (size_t)BB * (NN + MM) * 512);  // 8 MiB
    char*  accb  = ws + (size_t)BB * (NN + MM) * 512 + (size_t)8 * 1024 * 1024;
    float*        lsum  = (float*)accb;
    unsigned int* vcnt  = (unsigned int*)(accb + 64);
    unsigned int* flags = (unsigned int*)(accb + 128);
    unsigned int* done  = (unsigned int*)(accb + 256);

    hipLaunchKernelGGL(stream_kernel, dim3(6144), dim3(512), 0, stream,
                       z, x1, x2, normA, normB, codes, lsum, vcnt, flags, done);

    hipLaunchKernelGGL(fused_mfma_kernel, dim3(512), dim3(512), 0, stream,
                       codes, normA, normB, tp, bp, lsum, vcnt, flags, done, out);
}